// Round 10
// baseline (77.650 us; speedup 1.0000x reference)
//
#include <hip/hip_runtime.h>
#include <math.h>

// ---------------------------------------------------------------------------
// VQ-VAE eval forward.  N=65536 points x K=1024 codes x D=64, fp32 in/out.
// Distances via f16x2 split-precision MFMA (16x16x32_f16), numerics as R2-R9:
//   z = zh + 2^-12 zl', e = eh + 2^-12 el'  (lo pre-scaled by 4096)
//   argmax key m = (zh.eh - esq/2) + 2^-12 (zh.el' + zl'.eh)
// R10: PERSISTENT hi-codebook in LDS (128 KB, staged once) + lo-plane
// streamed L2->registers + ZERO barriers in the K-sweep.
//   256 blocks x 512 thr (8 waves) = 1 block/CU (LDS-forced). Wave owns 32
//   points, sweeps all 64 code-tiles barrier-free; depth-2 reg ping-pong for
//   lo; in-wave butterfly -> final indices. setprio(1) around MFMA clusters
//   (independent-wave regime). Verified-conflict-free XOR swizzle on hi.
// ---------------------------------------------------------------------------

#define QOUT_SZ  4194304            // 16*64*64*64
#define LOSS_OFF QOUT_SZ
#define IDX_OFF  (QOUT_SZ + 1)
#define PERP_OFF (QOUT_SZ + 1 + 65536)

typedef _Float16 f16x8 __attribute__((ext_vector_type(8)));
typedef _Float16 f16x4 __attribute__((ext_vector_type(4)));
typedef float    f32x4 __attribute__((ext_vector_type(4)));

// ws byte offsets
#define WS_EHI   0          // _Float16[65536] (128 KB)
#define WS_ELO   131072     // _Float16[65536] (128 KB)
#define WS_ESQ   262144     // float[1024]  (stores -0.5*||e||^2)
#define WS_HIST  266240     // float[1024]
#define WS_LOSS  270336     // float[256]

__device__ __forceinline__ void gll16(const void* g, void* l) {
    __builtin_amdgcn_global_load_lds(
        (const __attribute__((address_space(1))) void*)g,
        (__attribute__((address_space(3))) void*)l, 16, 0, 0);
}

// ---------------------------------------------------------------------------
// Prep: split-convert embedding, esq[k] = -0.5*||e_k||^2, zero hist. 64 x 256.
// ---------------------------------------------------------------------------
__global__ void vq_pre(const float* __restrict__ emb,
                       _Float16* __restrict__ ehi, _Float16* __restrict__ elo,
                       float* __restrict__ esq, float* __restrict__ hist) {
    const int t = threadIdx.x;
    const int g = blockIdx.x * 256 + t;          // float4 unit 0..16383
    float4 v = ((const float4*)emb)[g];
    float xs[4] = {v.x, v.y, v.z, v.w};
    f16x4 hi, lo;
    float ss = 0.f;
#pragma unroll
    for (int j = 0; j < 4; ++j) {
        _Float16 h = (_Float16)xs[j];
        hi[j] = h;
        lo[j] = (_Float16)((xs[j] - (float)h) * 4096.0f);
        ss = fmaf(xs[j], xs[j], ss);
    }
    ((f16x4*)ehi)[g] = hi;
    ((f16x4*)elo)[g] = lo;
    ss += __shfl_xor(ss, 1, 64);
    ss += __shfl_xor(ss, 2, 64);
    ss += __shfl_xor(ss, 4, 64);
    ss += __shfl_xor(ss, 8, 64);
    if ((t & 15) == 0) esq[g >> 4] = -0.5f * ss;
    if (blockIdx.x < 4) hist[blockIdx.x * 256 + t] = 0.f;
}

// ---------------------------------------------------------------------------
// Main. 256 blocks x 512 threads (8 waves). Block owns 256 points (4 bh rows);
// wave wv: row q=wv>>1, w-half side=(wv&1)*32 -> 32 points (2 pt-tiles).
// Hi-codebook resident in LDS; 64 code-tiles swept with zero barriers.
// ---------------------------------------------------------------------------
__launch_bounds__(512, 2)
__global__ void vq_main(const float* __restrict__ z,
                        const float* __restrict__ emb,
                        const _Float16* __restrict__ gehi,
                        const _Float16* __restrict__ gelo,
                        const float* __restrict__ gesq,
                        float* __restrict__ hist,
                        float* __restrict__ lossp,
                        float* __restrict__ out) {
    __shared__ __align__(16) char eshi[131072];   // [1024 codes][128 B] swz
    __shared__ float esql[1024];                  // -esq/2
    __shared__ int   idxs[256];
    __shared__ float redw[8];

    const int tid  = threadIdx.x;                 // 0..511
    const int blk  = blockIdx.x;                  // 0..255
    const int b    = blk >> 4;
    const int h0   = (blk & 15) << 2;             // 4 h-rows per block
    const int lane = tid & 63;
    const int wv   = tid >> 6;                    // 0..7
    const int q    = wv >> 1;                     // h row within block
    const int side = (wv & 1) << 5;               // w half (0 / 32)
    const int col  = lane & 15;                   // point row / code col
    const int g    = lane >> 4;                   // 0..3 K-slice quad

    // ---- esql into LDS ----
    esql[tid]       = gesq[tid];
    esql[tid + 512] = gesq[tid + 512];

    // ---- stage FULL hi-codebook once (linear dest, pre-swizzled source;
    //      swizzle verified conflict-free R4-R9) ----
    const char* gh = (const char*)gehi;
#pragma unroll
    for (int i = 0; i < 16; ++i) {
        const int u = tid + 512 * i;              // 16B unit 0..8191
        const int c = u >> 3;                     // code 0..1023
        const size_t so = (size_t)c * 128 + (size_t)(((u & 7) ^ (c & 7)) << 4);
        gll16(gh + so, eshi + i * 8192 + wv * 1024);
    }

    // ---- A fragments from global (overlaps staging DMA) ----
    const float* zb  = z + (size_t)b * 262144 + (size_t)h0 * 64;
    const float* zrw = zb + q * 64 + side + col;
    f16x8 Ah[2][2], Al[2][2];
#pragma unroll
    for (int pt = 0; pt < 2; ++pt) {
#pragma unroll
        for (int m = 0; m < 2; ++m) {
#pragma unroll
            for (int j = 0; j < 8; ++j) {
                int c = m * 32 + g * 8 + j;
                float x = zrw[pt * 16 + (size_t)c * 4096];
                _Float16 hh = (_Float16)x;
                Ah[pt][m][j] = hh;
                Al[pt][m][j] = (_Float16)((x - (float)hh) * 4096.0f);
            }
        }
    }

    __syncthreads();       // one-time: hi-codebook + esql resident (vmcnt+bar)

    // ---- per-lane invariant offsets ----
    const int inv0 = col * 128 + (((0 + g) ^ (col & 7)) << 4);   // hi, m=0 (swz)
    const int inv1 = col * 128 + (((4 + g) ^ (col & 7)) << 4);   // hi, m=1 (swz)
    const int gv0  = col * 128 + g * 16;                         // lo, m=0 (lin)
    const char* gl = (const char*)gelo;

    float best[2][4];
    int   besti[2][4];
#pragma unroll
    for (int pt = 0; pt < 2; ++pt)
#pragma unroll
        for (int r = 0; r < 4; ++r) { best[pt][r] = -3.4e38f; besti[pt][r] = 0; }

#define LDB(BH0, BH1, BL0, BL1, E2, ct) do {                              \
        const int o_ = (ct) * 2048;                                       \
        BH0 = *(const f16x8*)(eshi + o_ + inv0);                          \
        BH1 = *(const f16x8*)(eshi + o_ + inv1);                          \
        BL0 = *(const f16x8*)(gl + o_ + gv0);                             \
        BL1 = *(const f16x8*)(gl + o_ + gv0 + 64);                        \
        E2  = esql[(ct) * 16 + col];                                      \
    } while (0)

#define CMP(BH0, BH1, BL0, BL1, E2, ct) do {                              \
        const int kidx_ = (ct) * 16 + col;                                \
        _Pragma("unroll")                                                  \
        for (int pt_ = 0; pt_ < 2; ++pt_) {                                \
            f32x4 ah_ = {E2, E2, E2, E2};                                  \
            f32x4 ax_ = {0.f, 0.f, 0.f, 0.f};                              \
            __builtin_amdgcn_s_setprio(1);                                 \
            ah_ = __builtin_amdgcn_mfma_f32_16x16x32_f16(Ah[pt_][0], BH0, ah_, 0, 0, 0); \
            ah_ = __builtin_amdgcn_mfma_f32_16x16x32_f16(Ah[pt_][1], BH1, ah_, 0, 0, 0); \
            ax_ = __builtin_amdgcn_mfma_f32_16x16x32_f16(Ah[pt_][0], BL0, ax_, 0, 0, 0); \
            ax_ = __builtin_amdgcn_mfma_f32_16x16x32_f16(Ah[pt_][1], BL1, ax_, 0, 0, 0); \
            ax_ = __builtin_amdgcn_mfma_f32_16x16x32_f16(Al[pt_][0], BH0, ax_, 0, 0, 0); \
            ax_ = __builtin_amdgcn_mfma_f32_16x16x32_f16(Al[pt_][1], BH1, ax_, 0, 0, 0); \
            __builtin_amdgcn_s_setprio(0);                                 \
            _Pragma("unroll")                                              \
            for (int r_ = 0; r_ < 4; ++r_) {                               \
                float mv_ = fmaf(0x1p-12f, ax_[r_], ah_[r_]);              \
                if (mv_ > best[pt_][r_]) {                                 \
                    best[pt_][r_] = mv_; besti[pt_][r_] = kidx_;           \
                }                                                          \
            }                                                              \
        }                                                                  \
    } while (0)

    // ---- barrier-free sweep over 64 code-tiles, depth-2 reg ping-pong ----
    f16x8 Xh0, Xh1, Xl0, Xl1, Yh0, Yh1, Yl0, Yl1;
    float EX, EY;
    LDB(Xh0, Xh1, Xl0, Xl1, EX, 0);
    for (int ct = 0; ct < 62; ct += 2) {
        LDB(Yh0, Yh1, Yl0, Yl1, EY, ct + 1);
        CMP(Xh0, Xh1, Xl0, Xl1, EX, ct);
        LDB(Xh0, Xh1, Xl0, Xl1, EX, ct + 2);
        CMP(Yh0, Yh1, Yl0, Yl1, EY, ct + 1);
    }
    LDB(Yh0, Yh1, Yl0, Yl1, EY, 63);
    CMP(Xh0, Xh1, Xl0, Xl1, EX, 62);
    CMP(Yh0, Yh1, Yl0, Yl1, EY, 63);
#undef LDB
#undef CMP

    // ---- in-wave argmin over 16 code-cols = FINAL (np first-min) ----
#pragma unroll
    for (int mask = 1; mask <= 8; mask <<= 1) {
#pragma unroll
        for (int pt = 0; pt < 2; ++pt)
#pragma unroll
            for (int r = 0; r < 4; ++r) {
                float ov = __shfl_xor(best[pt][r], mask, 64);
                int   oi = __shfl_xor(besti[pt][r], mask, 64);
                if (ov > best[pt][r] ||
                    (ov == best[pt][r] && oi < besti[pt][r])) {
                    best[pt][r] = ov; besti[pt][r] = oi;
                }
            }
    }
    if (col == 0) {                               // lanes 0,16,32,48
#pragma unroll
        for (int pt = 0; pt < 2; ++pt)
#pragma unroll
            for (int r = 0; r < 4; ++r)
                idxs[q * 64 + side + pt * 16 + g * 4 + r] = besti[pt][r];
    }
    __syncthreads();

    // ---- indices out + histogram ----
    if (tid < 256) {
        int bi = idxs[tid];
        atomicAdd(&hist[bi], 1.0f);               // exact int counts
        out[(size_t)IDX_OFF + (size_t)blk * 256 + tid] = (float)bi;
    }
    __syncthreads();

    // ---- epilogue: quantized write (coalesced over w) + loss partial ----
    const int w  = tid & 63;
    const int hh = (tid >> 6) & 3;                // h row within block
    const int cq = tid >> 8;                      // 0..1 -> channels cq*32..+31
    const int pl = hh * 64 + w;
    const int idx = idxs[pl];
    const float* ev = emb + (size_t)idx * 64 + cq * 32;
    const float* zr = zb + hh * 64 + w;
    float* outq = out + (size_t)b * 262144 + (size_t)(h0 + hh) * 64 + w;
    float lsum = 0.f;
#pragma unroll
    for (int i = 0; i < 8; ++i) {
        float4 qv = *(const float4*)(ev + i * 4);
        float q4[4] = {qv.x, qv.y, qv.z, qv.w};
#pragma unroll
        for (int jj = 0; jj < 4; ++jj) {
            int c = cq * 32 + i * 4 + jj;
            float zv = zr[(size_t)c * 4096];      // L3-hot re-read
            outq[(size_t)c * 4096] = q4[jj];
            float d = q4[jj] - zv;
            lsum = fmaf(d, d, lsum);
        }
    }
#pragma unroll
    for (int off = 32; off > 0; off >>= 1)
        lsum += __shfl_xor(lsum, off, 64);
    if (lane == 0) redw[wv] = lsum;
    __syncthreads();
    if (tid == 0) {
        float s = 0.f;
#pragma unroll
        for (int i = 0; i < 8; ++i) s += redw[i];
        lossp[blk] = s;
    }
}

// ---------------------------------------------------------------------------
// Finalize: loss + perplexity, fixed-order tree. 1 x 1024.
// ---------------------------------------------------------------------------
__global__ void vq_fin(const float* __restrict__ hist,
                       const float* __restrict__ lossp,
                       float* __restrict__ out) {
    __shared__ float sh[1024];
    __shared__ float sl[1024];
    int t = threadIdx.x;
    float hc = hist[t];
    float p  = hc * (1.0f / 65536.0f);
    sh[t] = p * logf(p + 1e-10f);
    sl[t] = (t < 256) ? lossp[t] : 0.f;
    __syncthreads();
    for (int s = 512; s > 0; s >>= 1) {
        if (t < s) { sh[t] += sh[t + s]; sl[t] += sl[t + s]; }
        __syncthreads();
    }
    if (t == 0) {
        out[LOSS_OFF] = 0.25f * sl[0] / (float)QOUT_SZ;
        out[PERP_OFF] = expf(-sh[0]);
    }
}

extern "C" void kernel_launch(void* const* d_in, const int* in_sizes, int n_in,
                              void* d_out, int out_size, void* d_ws, size_t ws_size,
                              hipStream_t stream) {
    const float* z   = (const float*)d_in[0];   // [16,64,64,64] fp32 NCHW
    const float* emb = (const float*)d_in[1];   // [1024,64] fp32
    float* out = (float*)d_out;
    char*  ws  = (char*)d_ws;

    _Float16* ehi   = (_Float16*)(ws + WS_EHI);
    _Float16* elo   = (_Float16*)(ws + WS_ELO);
    float*    esq   = (float*)(ws + WS_ESQ);
    float*    hist  = (float*)(ws + WS_HIST);
    float*    lossp = (float*)(ws + WS_LOSS);

    vq_pre<<<64, 256, 0, stream>>>(emb, ehi, elo, esq, hist);
    vq_main<<<256, 512, 0, stream>>>(z, emb, ehi, elo, esq, hist, lossp, out);
    vq_fin<<<1, 1024, 0, stream>>>(hist, lossp, out);
}